// Round 6
// baseline (71.197 us; speedup 1.0000x reference)
//
#include <hip/hip_runtime.h>

typedef float v2f __attribute__((ext_vector_type(2)));

#define Q_MIN 0.5f
#define MAXK 512
#define KHALF 256
#define BLK 256
#define GSC 256
#define NBM 1024
#define MAXN 131072

struct alignas(64) HitRec { float4 c0, c1, c2, pad; };
// c0 = x[0..3], c1 = x[4..7], c2 = {-|x|^2, q_i, yi_bits, 0}

struct alignas(16) PlainRec { float a[8]; float u, q, r0, r1; };  // 48B
struct alignas(16) PairRec2 { float c[20]; };  // halves interleaved: (k, k+256)

struct Scratch {
  unsigned long long blk_packed[GSC][MAXK];   // 1 MB
  unsigned int blk_fc[GSC][MAXK];             // 0.5 MB
  PairRec2 tab2[KHALF];
  PlainRec plain[MAXK];
  float fcenterf[MAXK];
  float partial_lv[NBM];
  float partial_bkg[GSC];
  float partial_cnt[GSC];
  unsigned int ctr;
  unsigned int _p[15];
  HitRec recs[MAXN];                          // 8 MB
};

__device__ __forceinline__ v2f bc2(float s) { return (v2f){s, s}; }

// ---------------- dispatch 1: scatter + hit-record prep ----------------
__global__ void __launch_bounds__(BLK) k_scatprep(
    const float* __restrict__ x, const float* __restrict__ f,
    const int* __restrict__ y, const int* __restrict__ ei, const int* __restrict__ ej,
    int n, int e, Scratch* __restrict__ ws) {
  __shared__ unsigned long long sp[MAXK];
  __shared__ unsigned int sf[MAXK];
  for (int t = threadIdx.x; t < MAXK; t += BLK) { sp[t] = 0ull; sf[t] = 0u; }
  __syncthreads();
  float bk = 0.f, ct = 0.f;
  int lim = MAXN > e ? MAXN : e;
  for (int t = blockIdx.x * BLK + threadIdx.x; t < lim; t += GSC * BLK) {
    if (t < n) {
      int yi = y[t];
      float fv = f[t];
      float a = atanhf(fv);
      float q = fmaf(a, a, Q_MIN);
      const float4* xp = (const float4*)(x + (size_t)t * 8);
      float4 v0 = xp[0], v1 = xp[1];
      float x2 = v0.x*v0.x + v0.y*v0.y + v0.z*v0.z + v0.w*v0.w
               + v1.x*v1.x + v1.y*v1.y + v1.z*v1.z + v1.w*v1.w;
      HitRec* r = &ws->recs[t];
      r->c0 = v0; r->c1 = v1;
      r->c2 = make_float4(-x2, q, __int_as_float(yi), 0.f);
      if (yi >= 0 && yi < MAXK) {
        unsigned long long p = ((unsigned long long)__float_as_uint(q) << 32)
                             | (unsigned long long)(0xFFFFFFFFu - (unsigned)t);
        atomicMax(&sp[yi], p);
      } else if (yi == -1) { bk += fv; ct += 1.f; }
    } else if (t < MAXN) {
      // zero-pad so k_main can stream past n with q_i = 0
      HitRec* r = &ws->recs[t];
      r->c0 = make_float4(0.f, 0.f, 0.f, 0.f);
      r->c1 = make_float4(0.f, 0.f, 0.f, 0.f);
      r->c2 = make_float4(0.f, 0.f, __int_as_float(-2), 0.f);
    }
    if (t < e) {
      int j = ej[t];
      if (j >= 0 && j < MAXK)
        atomicMax(&sf[j], __float_as_uint(f[ei[t]]));  // f > 0: bits-max == fmax
    }
  }
  __syncthreads();
  for (int t = threadIdx.x; t < MAXK; t += BLK) {
    ws->blk_packed[blockIdx.x][t] = sp[t];
    ws->blk_fc[blockIdx.x][t] = sf[t];
  }
  for (int o = 32; o > 0; o >>= 1) { bk += __shfl_down(bk, o, 64); ct += __shfl_down(ct, o, 64); }
  __shared__ float rb[BLK / 64], rc[BLK / 64];
  int wid = threadIdx.x >> 6, lane = threadIdx.x & 63;
  if (lane == 0) { rb[wid] = bk; rc[wid] = ct; }
  __syncthreads();
  if (threadIdx.x == 0) {
    float sb = 0.f, sc = 0.f;
    #pragma unroll
    for (int w = 0; w < BLK / 64; ++w) { sb += rb[w]; sc += rc[w]; }
    ws->partial_bkg[blockIdx.x] = sb;
    ws->partial_cnt[blockIdx.x] = sc;
  }
}

// ---------------- dispatch 2: reduce tables, build center records ----------------
// 8 blocks; 4 threads per k (64 tables each) then shfl-max combine.
__global__ void __launch_bounds__(BLK) k_centers(
    const float* __restrict__ x, int n, Scratch* __restrict__ ws) {
  int tid = threadIdx.x;
  int k = blockIdx.x * 64 + (tid >> 2);
  int sub = tid & 3;
  unsigned long long m = 0ull;
  unsigned int fcb = 0u;
  for (int b = sub; b < GSC; b += 4) {
    unsigned long long v = ws->blk_packed[b][k];
    m = v > m ? v : m;
    unsigned int w = ws->blk_fc[b][k];
    fcb = w > fcb ? w : fcb;
  }
  #pragma unroll
  for (int o = 1; o < 4; o <<= 1) {
    unsigned long long vm = __shfl_xor(m, o, 64);
    m = vm > m ? vm : m;
    unsigned int vf = __shfl_xor(fcb, o, 64);
    fcb = vf > fcb ? vf : fcb;
  }
  if (sub == 0) {
    float q = 0.f, u = 0.f;
    float a[8];
    #pragma unroll
    for (int j = 0; j < 8; ++j) a[j] = 0.f;
    if (m != 0ull) {
      q = __uint_as_float((unsigned)(m >> 32));
      unsigned idx = 0xFFFFFFFFu - (unsigned)(m & 0xFFFFFFFFull);
      if (idx < (unsigned)n) {
        const float* xp = x + (size_t)idx * 8;
        float s2 = 0.f;
        #pragma unroll
        for (int j = 0; j < 8; ++j) { float v = xp[j]; s2 = fmaf(v, v, s2); a[j] = 2.f * v; }
        u = 1.f - s2;
      }
    }
    PlainRec* pr = &ws->plain[k];
    #pragma unroll
    for (int j = 0; j < 8; ++j) pr->a[j] = a[j];
    pr->u = u; pr->q = q; pr->r0 = 0.f; pr->r1 = 0.f;
    float* rec = (float*)&ws->tab2[k & (KHALF - 1)];
    int h = k >> 8;
    #pragma unroll
    for (int j = 0; j < 8; ++j) rec[2 * j + h] = a[j];
    rec[16 + h] = u;
    rec[18 + h] = q;
    ws->fcenterf[k] = __uint_as_float(fcb);
  }
}

// ---------------- dispatch 3: transposed main + fused final ----------------
struct HR { float4 c0, c1, c2; };
__device__ __forceinline__ HR ldrec(const HitRec* __restrict__ p) {
  const float4* q4 = (const float4*)p;
  HR h; h.c0 = q4[0]; h.c1 = q4[1]; h.c2 = q4[2];
  return h;
}

#define STEP(H)                                                              \
  { v2f r_ = u2 + bc2((H).c2.x);                                             \
    r_ = __builtin_elementwise_fma(bc2((H).c0.x), a0, r_);                   \
    r_ = __builtin_elementwise_fma(bc2((H).c0.y), a1, r_);                   \
    r_ = __builtin_elementwise_fma(bc2((H).c0.z), a2, r_);                   \
    r_ = __builtin_elementwise_fma(bc2((H).c0.w), a3, r_);                   \
    r_ = __builtin_elementwise_fma(bc2((H).c1.x), a4, r_);                   \
    r_ = __builtin_elementwise_fma(bc2((H).c1.y), a5, r_);                   \
    r_ = __builtin_elementwise_fma(bc2((H).c1.z), a6, r_);                   \
    r_ = __builtin_elementwise_fma(bc2((H).c1.w), a7, r_);                   \
    v2f xv_ = __builtin_elementwise_min(__builtin_elementwise_max(r_, zero2), one2); \
    acc = __builtin_elementwise_fma(xv_, bc2((H).c2.y), acc); }

__global__ void __launch_bounds__(BLK) k_main(
    const HitRec* __restrict__ recs, const PairRec2* __restrict__ tab2,
    const PlainRec* __restrict__ plain, const int* __restrict__ kptr,
    int n, int hpb, Scratch* __restrict__ ws, float* __restrict__ out) {
  const float4* tp = (const float4*)&tab2[threadIdx.x];
  float4 t0 = tp[0], t1 = tp[1], t2 = tp[2], t3 = tp[3], t4 = tp[4];
  v2f a0 = {t0.x, t0.y}, a1 = {t0.z, t0.w}, a2 = {t1.x, t1.y}, a3 = {t1.z, t1.w};
  v2f a4 = {t2.x, t2.y}, a5 = {t2.z, t2.w}, a6 = {t3.x, t3.y}, a7 = {t3.z, t3.w};
  v2f u2 = {t4.x, t4.y}, q2 = {t4.z, t4.w};

  int i0 = blockIdx.x * hpb;
  int iend = i0 + hpb;          // uniform; pad recs guarantee q=0 past n

  // phase 1: member-term fixup (one term per hit in this block's slice)
  float fix = 0.f;
  for (int i = i0 + threadIdx.x; i < iend; i += BLK) {
    float4 c2 = recs[i].c2;
    int yi = __float_as_int(c2.z);
    if (yi >= 0 && yi < MAXK) {
      float4 h0 = recs[i].c0, h1 = recs[i].c1;
      const float4* pr4 = (const float4*)&plain[yi];
      float4 f0 = pr4[0], f1 = pr4[1], f2 = pr4[2];
      float r = f2.x + c2.x;
      r = fmaf(h0.x, f0.x, r); r = fmaf(h0.y, f0.y, r);
      r = fmaf(h0.z, f0.z, r); r = fmaf(h0.w, f0.w, r);
      r = fmaf(h1.x, f1.x, r); r = fmaf(h1.y, f1.y, r);
      r = fmaf(h1.z, f1.z, r); r = fmaf(h1.w, f1.w, r);
      float xinv = __builtin_amdgcn_fmed3f(r, 0.f, 1.f);
      float xd = fmaxf(1.f - r, 0.f);
      fix += (xd - xinv) * f2.y * c2.y;
    }
  }

  // phase 2: stream hits with 4-deep rotating prefetch; zero LDS, pure pk-f32
  v2f acc = {0.f, 0.f};
  v2f zero2 = {0.f, 0.f}, one2 = {1.f, 1.f};
  HR A = ldrec(recs + i0), B = ldrec(recs + i0 + 1),
     C = ldrec(recs + i0 + 2), D = ldrec(recs + i0 + 3);
  for (int i = i0; i < iend; i += 4) {
    STEP(A); A = ldrec(recs + i + 4);
    STEP(B); B = ldrec(recs + i + 5);
    STEP(C); C = ldrec(recs + i + 6);
    STEP(D); D = ldrec(recs + i + 7);
  }

  float lv = fmaf(acc[0], q2[0], fmaf(acc[1], q2[1], fix));
  for (int o = 32; o > 0; o >>= 1) lv += __shfl_down(lv, o, 64);
  __shared__ float rl[BLK / 64];
  int wid = threadIdx.x >> 6, lane = threadIdx.x & 63;
  if (lane == 0) rl[wid] = lv;
  __syncthreads();
  if (threadIdx.x == 0) {
    float s = 0.f;
    #pragma unroll
    for (int w = 0; w < BLK / 64; ++w) s += rl[w];
    ws->partial_lv[blockIdx.x] = s;
  }

  // fused final: fence + counter, last block reduces everything (fixed order)
  __shared__ int amLast;
  if (threadIdx.x == 0) {
    __threadfence();
    unsigned old = atomicAdd(&ws->ctr, 1u);
    amLast = (old == NBM - 1) ? 1 : 0;
  }
  __syncthreads();
  if (amLast) {
    __threadfence();
    int K = kptr[0]; if (K > MAXK) K = MAXK;
    int tid = threadIdx.x;
    float a = 0.f, b = 0.f, c = 0.f, d = 0.f;
    for (int t = tid; t < NBM; t += BLK) a += ws->partial_lv[t];
    for (int t = tid; t < GSC; t += BLK) { b += ws->partial_bkg[t]; c += ws->partial_cnt[t]; }
    for (int t = tid; t < MAXK; t += BLK) d += ws->fcenterf[t];  // 0 for t >= K
    __shared__ float sa[BLK], sb[BLK], sc[BLK], sd[BLK];
    sa[tid] = a; sb[tid] = b; sc[tid] = c; sd[tid] = d;
    __syncthreads();
    for (int o = BLK / 2; o > 0; o >>= 1) {
      if (tid < o) {
        sa[tid] += sa[tid + o]; sb[tid] += sb[tid + o];
        sc[tid] += sc[tid + o]; sd[tid] += sd[tid + o];
      }
      __syncthreads();
    }
    if (tid == 0) {
      float b1 = 1.f - sd[0] / (float)K;
      float b2 = sb[0] / sc[0];            // S_B = 1
      out[0] = (b1 + b2) + sa[0] / (float)n;
    }
  }
}

extern "C" void kernel_launch(void* const* d_in, const int* in_sizes, int n_in,
                              void* d_out, int out_size, void* d_ws, size_t ws_size,
                              hipStream_t stream) {
  const float* x = (const float*)d_in[0];
  const float* f = (const float*)d_in[1];
  const int*   y = (const int*)d_in[2];
  const int*  ei = (const int*)d_in[3];
  const int*  ej = (const int*)d_in[4];
  const int* kptr = (const int*)d_in[5];
  float* out = (float*)d_out;
  int n = in_sizes[1];
  int e = in_sizes[3];
  Scratch* ws = (Scratch*)d_ws;

  int hpb = ((n + NBM - 1) / NBM + 3) & ~3;   // multiple of 4; NBM*hpb+8 <= MAXN for n=100k

  hipMemsetAsync(&ws->ctr, 0, sizeof(unsigned int), stream);
  hipLaunchKernelGGL(k_scatprep, dim3(GSC),      dim3(BLK), 0, stream, x, f, y, ei, ej, n, e, ws);
  hipLaunchKernelGGL(k_centers,  dim3(MAXK/64),  dim3(BLK), 0, stream, x, n, ws);
  hipLaunchKernelGGL(k_main,     dim3(NBM),      dim3(BLK), 0, stream,
                     ws->recs, ws->tab2, ws->plain, kptr, n, hpb, ws, out);
}

// Round 7
// 59.919 us; speedup vs baseline: 1.1882x; 1.1882x over previous
//
#include <hip/hip_runtime.h>

typedef float v2f __attribute__((ext_vector_type(2)));

#define Q_MIN 0.5f
#define MAXK 512
#define KHALF 256
#define BLK 256
#define GSC 128
#define NBM 1024
#define MAXN 131072

struct alignas(16) HitRec { float4 c0, c1, c2; };                 // 48B: x[0..3], x[4..7], {-|x|^2, q_i, yi_bits, 0}
struct alignas(16) PlainRec { float a[8]; float u, q, r0, r1; };  // 48B
struct alignas(16) PairRec2 { float c[20]; };                     // 80B, halves interleaved (k, k+256)

struct Scratch {
  unsigned long long blk_packed[GSC][MAXK];
  unsigned int blk_fc[GSC][MAXK];
  float partial_bkg[GSC];
  float partial_cnt[GSC];
  PairRec2 tab2[KHALF];
  PlainRec plain[MAXK];
  float plv[NBM];
  float bconst;
  unsigned int ctr;
  unsigned int _pad[2];
  HitRec recs[MAXN];
};

__device__ __forceinline__ v2f bc2(float s) { return (v2f){s, s}; }

// ---------- dispatch 1: LDS-atomic scatter + hit-record prep ----------
__global__ void __launch_bounds__(BLK) k_scatprep(
    const float* __restrict__ x, const float* __restrict__ f,
    const int* __restrict__ y, const int* __restrict__ ei, const int* __restrict__ ej,
    int n, int e, int limpad, Scratch* __restrict__ ws) {
  __shared__ unsigned long long sp[MAXK];
  __shared__ unsigned int sf[MAXK];
  for (int t = threadIdx.x; t < MAXK; t += BLK) { sp[t] = 0ull; sf[t] = 0u; }
  __syncthreads();
  float bk = 0.f, ct = 0.f;
  int lim = limpad > e ? limpad : e;
  for (int t = blockIdx.x * BLK + threadIdx.x; t < lim; t += GSC * BLK) {
    if (t < n) {
      int yi = y[t];
      float fv = f[t];
      float a = atanhf(fv);
      float q = fmaf(a, a, Q_MIN);
      const float4* xp = (const float4*)(x + (size_t)t * 8);
      float4 v0 = xp[0], v1 = xp[1];
      float x2 = v0.x*v0.x + v0.y*v0.y + v0.z*v0.z + v0.w*v0.w
               + v1.x*v1.x + v1.y*v1.y + v1.z*v1.z + v1.w*v1.w;
      HitRec* r = &ws->recs[t];
      r->c0 = v0; r->c1 = v1;
      r->c2 = make_float4(-x2, q, __int_as_float(yi), 0.f);
      if (yi >= 0 && yi < MAXK) {
        unsigned long long p = ((unsigned long long)__float_as_uint(q) << 32)
                             | (unsigned long long)(0xFFFFFFFFu - (unsigned)t);
        atomicMax(&sp[yi], p);
      } else if (yi == -1) { bk += fv; ct += 1.f; }
    } else if (t < limpad) {
      HitRec* r = &ws->recs[t];           // q_i = 0 pad: contributes nothing
      r->c0 = make_float4(0.f, 0.f, 0.f, 0.f);
      r->c1 = make_float4(0.f, 0.f, 0.f, 0.f);
      r->c2 = make_float4(0.f, 0.f, __int_as_float(-2), 0.f);
    }
    if (t < e) {
      int j = ej[t];
      if (j >= 0 && j < MAXK)
        atomicMax(&sf[j], __float_as_uint(f[ei[t]]));  // f > 0: bits-max == fmax
    }
  }
  __syncthreads();
  for (int t = threadIdx.x; t < MAXK; t += BLK) {
    ws->blk_packed[blockIdx.x][t] = sp[t];
    ws->blk_fc[blockIdx.x][t] = sf[t];
  }
  for (int o = 32; o > 0; o >>= 1) { bk += __shfl_down(bk, o, 64); ct += __shfl_down(ct, o, 64); }
  __shared__ float rb[BLK / 64], rc[BLK / 64];
  int wid = threadIdx.x >> 6, lane = threadIdx.x & 63;
  if (lane == 0) { rb[wid] = bk; rc[wid] = ct; }
  __syncthreads();
  if (threadIdx.x == 0) {
    float sb = 0.f, sc = 0.f;
    #pragma unroll
    for (int w = 0; w < BLK / 64; ++w) { sb += rb[w]; sc += rc[w]; }
    ws->partial_bkg[blockIdx.x] = sb;
    ws->partial_cnt[blockIdx.x] = sc;
  }
}

// ---------- dispatch 2: table reduce + center records + b1+b2 + ctr reset ----------
__global__ void __launch_bounds__(512) k_centers(
    const float* __restrict__ x, const int* __restrict__ kptr, int n,
    Scratch* __restrict__ ws) {
  int k = threadIdx.x;            // 0..511, one class per thread
  unsigned long long m = 0ull;
  unsigned int fcb = 0u;
  #pragma unroll 4
  for (int b = 0; b < GSC; ++b) {
    unsigned long long v = ws->blk_packed[b][k]; m = v > m ? v : m;
    unsigned int w = ws->blk_fc[b][k]; if (w > fcb) fcb = w;
  }
  float q = 0.f, u = 0.f;
  float a[8];
  #pragma unroll
  for (int j = 0; j < 8; ++j) a[j] = 0.f;
  if (m != 0ull) {
    q = __uint_as_float((unsigned)(m >> 32));
    unsigned idx = 0xFFFFFFFFu - (unsigned)(m & 0xFFFFFFFFull);
    if (idx < (unsigned)n) {
      const float* xp = x + (size_t)idx * 8;
      float s2 = 0.f;
      #pragma unroll
      for (int j = 0; j < 8; ++j) { float v = xp[j]; s2 = fmaf(v, v, s2); a[j] = 2.f * v; }
      u = 1.f - s2;
    }
  }
  PlainRec* pr = &ws->plain[k];
  #pragma unroll
  for (int j = 0; j < 8; ++j) pr->a[j] = a[j];
  pr->u = u; pr->q = q; pr->r0 = 0.f; pr->r1 = 0.f;
  float* rec = (float*)&ws->tab2[k & (KHALF - 1)];
  int h = k >> 8;
  #pragma unroll
  for (int j = 0; j < 8; ++j) rec[2 * j + h] = a[j];
  rec[16 + h] = u;
  rec[18 + h] = q;

  // block-wide sums: fcenter over 512 ks, bkg/cnt over GSC partials
  __shared__ float s1[512], s2a[512], s3[512];
  s1[k] = __uint_as_float(fcb);
  s2a[k] = (k < GSC) ? ws->partial_bkg[k] : 0.f;
  s3[k] = (k < GSC) ? ws->partial_cnt[k] : 0.f;
  __syncthreads();
  for (int o = 256; o > 0; o >>= 1) {
    if (k < o) { s1[k] += s1[k + o]; s2a[k] += s2a[k + o]; s3[k] += s3[k + o]; }
    __syncthreads();
  }
  if (k == 0) {
    int K = kptr[0]; if (K > MAXK) K = MAXK;
    float b1 = 1.f - s1[0] / (float)K;
    float b2 = s2a[0] / s3[0];                       // S_B = 1
    __hip_atomic_store(&ws->bconst, b1 + b2, __ATOMIC_RELAXED, __HIP_MEMORY_SCOPE_AGENT);
    __hip_atomic_store(&ws->ctr, 0u, __ATOMIC_RELAXED, __HIP_MEMORY_SCOPE_AGENT);
  }
}

// ---------- dispatch 3: transposed main + atomics-fused final ----------
__global__ void __launch_bounds__(BLK, 4) k_main(
    const HitRec* __restrict__ recs, const PairRec2* __restrict__ tab2,
    const PlainRec* __restrict__ plain, int n, int hpb,
    Scratch* __restrict__ ws, float* __restrict__ out) {
  const float4* tp = (const float4*)&tab2[threadIdx.x];
  float4 t0 = tp[0], t1 = tp[1], t2 = tp[2], t3 = tp[3], t4 = tp[4];
  v2f a0 = {t0.x, t0.y}, a1 = {t0.z, t0.w}, a2 = {t1.x, t1.y}, a3 = {t1.z, t1.w};
  v2f a4 = {t2.x, t2.y}, a5 = {t2.z, t2.w}, a6 = {t3.x, t3.y}, a7 = {t3.z, t3.w};
  v2f u2 = {t4.x, t4.y}, q2 = {t4.z, t4.w};

  int i0 = blockIdx.x * hpb;
  int iend = i0 + hpb;                 // pads guarantee q_i = 0 past n

  // phase 1: member-term fixup (one term per hit in this slice)
  float fix = 0.f;
  for (int i = i0 + threadIdx.x; i < iend; i += BLK) {
    float4 c2 = recs[i].c2;
    int yi = __float_as_int(c2.z);
    if (yi >= 0 && yi < MAXK) {
      float4 h0 = recs[i].c0, h1 = recs[i].c1;
      const float4* pr4 = (const float4*)&plain[yi];
      float4 f0 = pr4[0], f1 = pr4[1], f2 = pr4[2];
      float r = f2.x + c2.x;
      r = fmaf(h0.x, f0.x, r); r = fmaf(h0.y, f0.y, r);
      r = fmaf(h0.z, f0.z, r); r = fmaf(h0.w, f0.w, r);
      r = fmaf(h1.x, f1.x, r); r = fmaf(h1.y, f1.y, r);
      r = fmaf(h1.z, f1.z, r); r = fmaf(h1.w, f1.w, r);
      float xinv = __builtin_amdgcn_fmed3f(r, 0.f, 1.f);
      float xd = fmaxf(1.f - r, 0.f);
      fix += (xd - xinv) * f2.y * c2.y;
    }
  }

  // phase 2: stream hits; 12 pk-ish ops per thread per hit, zero LDS
  v2f acc = {0.f, 0.f};
  v2f zero2 = {0.f, 0.f}, one2 = {1.f, 1.f};
  #pragma unroll 4
  for (int i = i0; i < iend; ++i) {
    const float4* q4 = (const float4*)&recs[i];
    float4 h0 = q4[0], h1 = q4[1], h2 = q4[2];     // wave-uniform
    v2f r = u2 + bc2(h2.x);
    r = __builtin_elementwise_fma(bc2(h0.x), a0, r);
    r = __builtin_elementwise_fma(bc2(h0.y), a1, r);
    r = __builtin_elementwise_fma(bc2(h0.z), a2, r);
    r = __builtin_elementwise_fma(bc2(h0.w), a3, r);
    r = __builtin_elementwise_fma(bc2(h1.x), a4, r);
    r = __builtin_elementwise_fma(bc2(h1.y), a5, r);
    r = __builtin_elementwise_fma(bc2(h1.z), a6, r);
    r = __builtin_elementwise_fma(bc2(h1.w), a7, r);
    v2f xinv = __builtin_elementwise_min(__builtin_elementwise_max(r, zero2), one2);
    acc = __builtin_elementwise_fma(xinv, bc2(h2.y), acc);
  }

  float lv = fmaf(acc[0], q2[0], fmaf(acc[1], q2[1], fix));
  for (int o = 32; o > 0; o >>= 1) lv += __shfl_down(lv, o, 64);
  __shared__ float rl[BLK / 64];
  int wid = threadIdx.x >> 6, lane = threadIdx.x & 63;
  if (lane == 0) rl[wid] = lv;
  __syncthreads();

  // fused final: relaxed agent-scope publish + acq_rel counter (NO threadfence)
  __shared__ int amLast;
  if (threadIdx.x == 0) {
    float s = 0.f;
    #pragma unroll
    for (int w = 0; w < BLK / 64; ++w) s += rl[w];
    __hip_atomic_store(&ws->plv[blockIdx.x], s, __ATOMIC_RELAXED, __HIP_MEMORY_SCOPE_AGENT);
    unsigned old = __hip_atomic_fetch_add(&ws->ctr, 1u, __ATOMIC_ACQ_REL, __HIP_MEMORY_SCOPE_AGENT);
    amLast = (old == NBM - 1) ? 1 : 0;
  }
  __syncthreads();
  if (amLast) {
    int tid = threadIdx.x;
    float s = 0.f;
    for (int t = tid; t < NBM; t += BLK)
      s += __hip_atomic_load(&ws->plv[t], __ATOMIC_RELAXED, __HIP_MEMORY_SCOPE_AGENT);
    __shared__ float sa[BLK];
    sa[tid] = s;
    __syncthreads();
    for (int o = BLK / 2; o > 0; o >>= 1) {
      if (tid < o) sa[tid] += sa[tid + o];
      __syncthreads();
    }
    if (tid == 0) {
      float bc = __hip_atomic_load(&ws->bconst, __ATOMIC_RELAXED, __HIP_MEMORY_SCOPE_AGENT);
      out[0] = bc + sa[0] / (float)n;
    }
  }
}

extern "C" void kernel_launch(void* const* d_in, const int* in_sizes, int n_in,
                              void* d_out, int out_size, void* d_ws, size_t ws_size,
                              hipStream_t stream) {
  const float* x = (const float*)d_in[0];
  const float* f = (const float*)d_in[1];
  const int*   y = (const int*)d_in[2];
  const int*  ei = (const int*)d_in[3];
  const int*  ej = (const int*)d_in[4];
  const int* kptr = (const int*)d_in[5];
  float* out = (float*)d_out;
  int n = in_sizes[1];
  int e = in_sizes[3];
  Scratch* ws = (Scratch*)d_ws;

  int hpb = ((n + NBM - 1) / NBM + 3) & ~3;   // hits per k_main block, multiple of 4
  int limpad = NBM * hpb;                      // 102400 for n=100k, < MAXN
  if (limpad > MAXN) limpad = MAXN;

  hipLaunchKernelGGL(k_scatprep, dim3(GSC), dim3(BLK), 0, stream,
                     x, f, y, ei, ej, n, e, limpad, ws);
  hipLaunchKernelGGL(k_centers,  dim3(1),   dim3(512), 0, stream, x, kptr, n, ws);
  hipLaunchKernelGGL(k_main,     dim3(NBM), dim3(BLK), 0, stream,
                     ws->recs, ws->tab2, ws->plain, n, hpb, ws, out);
}

// Round 8
// 42.190 us; speedup vs baseline: 1.6875x; 1.4202x over previous
//
#include <hip/hip_runtime.h>

typedef float v2f __attribute__((ext_vector_type(2)));

#define Q_MIN 0.5f
#define MAXK 512
#define KHALF 256
#define BLK 256
#define GSC 128
#define NBM 1024
#define MAXN 131072

struct alignas(16) HitRec { float4 c0, c1, c2; };                 // x[0..3], x[4..7], {-|x|^2, q_i, yi_bits, 0}
struct alignas(16) PlainRec { float a[8]; float u, q, r0, r1; };  // 48B
struct alignas(16) PairRec2 { float c[20]; };                     // 80B, halves interleaved (k, k+256)

struct Scratch {
  unsigned long long blk_packed[GSC][MAXK];
  unsigned int blk_fc[GSC][MAXK];
  float partial_bkg[GSC];
  float partial_cnt[GSC];
  PairRec2 tab2[KHALF];
  PlainRec plain[MAXK];
  float fcenterf[MAXK];
  float plv[NBM];
  unsigned int ctr;
  unsigned int _pad[3];
  HitRec recs[MAXN];
};

__device__ __forceinline__ v2f bc2(float s) { return (v2f){s, s}; }

// ---------- dispatch 1: LDS-atomic scatter + hit-record prep ----------
__global__ void __launch_bounds__(BLK) k_scatprep(
    const float* __restrict__ x, const float* __restrict__ f,
    const int* __restrict__ y, const int* __restrict__ ei, const int* __restrict__ ej,
    int n, int e, int limpad, Scratch* __restrict__ ws) {
  __shared__ unsigned long long sp[MAXK];
  __shared__ unsigned int sf[MAXK];
  for (int t = threadIdx.x; t < MAXK; t += BLK) { sp[t] = 0ull; sf[t] = 0u; }
  __syncthreads();
  float bk = 0.f, ct = 0.f;
  int lim = limpad > e ? limpad : e;
  for (int t = blockIdx.x * BLK + threadIdx.x; t < lim; t += GSC * BLK) {
    if (t < n) {
      int yi = y[t];
      float fv = f[t];
      float a = atanhf(fv);
      float q = fmaf(a, a, Q_MIN);
      const float4* xp = (const float4*)(x + (size_t)t * 8);
      float4 v0 = xp[0], v1 = xp[1];
      float x2 = v0.x*v0.x + v0.y*v0.y + v0.z*v0.z + v0.w*v0.w
               + v1.x*v1.x + v1.y*v1.y + v1.z*v1.z + v1.w*v1.w;
      HitRec* r = &ws->recs[t];
      r->c0 = v0; r->c1 = v1;
      r->c2 = make_float4(-x2, q, __int_as_float(yi), 0.f);
      if (yi >= 0 && yi < MAXK) {
        unsigned long long p = ((unsigned long long)__float_as_uint(q) << 32)
                             | (unsigned long long)(0xFFFFFFFFu - (unsigned)t);
        atomicMax(&sp[yi], p);
      } else if (yi == -1) { bk += fv; ct += 1.f; }
    } else if (t < limpad) {
      HitRec* r = &ws->recs[t];           // q_i = 0 pad: contributes nothing
      r->c0 = make_float4(0.f, 0.f, 0.f, 0.f);
      r->c1 = make_float4(0.f, 0.f, 0.f, 0.f);
      r->c2 = make_float4(0.f, 0.f, __int_as_float(-2), 0.f);
    }
    if (t < e) {
      int j = ej[t];
      if (j >= 0 && j < MAXK)
        atomicMax(&sf[j], __float_as_uint(f[ei[t]]));  // f > 0: bits-max == fmax
    }
  }
  __syncthreads();
  for (int t = threadIdx.x; t < MAXK; t += BLK) {
    ws->blk_packed[blockIdx.x][t] = sp[t];
    ws->blk_fc[blockIdx.x][t] = sf[t];
  }
  for (int o = 32; o > 0; o >>= 1) { bk += __shfl_down(bk, o, 64); ct += __shfl_down(ct, o, 64); }
  __shared__ float rb[BLK / 64], rc[BLK / 64];
  int wid = threadIdx.x >> 6, lane = threadIdx.x & 63;
  if (lane == 0) { rb[wid] = bk; rc[wid] = ct; }
  __syncthreads();
  if (threadIdx.x == 0) {
    float sb = 0.f, sc = 0.f;
    #pragma unroll
    for (int w = 0; w < BLK / 64; ++w) { sb += rb[w]; sc += rc[w]; }
    ws->partial_bkg[blockIdx.x] = sb;
    ws->partial_cnt[blockIdx.x] = sc;
  }
}

// ---------- dispatch 2: parallel table reduce (64 blocks, 32 lanes/class) ----------
__global__ void __launch_bounds__(BLK) k_centers(
    const float* __restrict__ x, int n, Scratch* __restrict__ ws) {
  if (blockIdx.x == 0 && threadIdx.x == 0)
    __hip_atomic_store(&ws->ctr, 0u, __ATOMIC_RELAXED, __HIP_MEMORY_SCOPE_AGENT);
  int tid = threadIdx.x;
  int k = blockIdx.x * 8 + (tid >> 5);   // 8 classes per block
  int sub = tid & 31;
  unsigned long long m = 0ull;
  unsigned int fcb = 0u;
  for (int b = sub; b < GSC; b += 32) {   // 4 iterations, deep TLP across 64 blocks
    unsigned long long v = ws->blk_packed[b][k]; m = v > m ? v : m;
    unsigned int w = ws->blk_fc[b][k]; if (w > fcb) fcb = w;
  }
  #pragma unroll
  for (int o = 1; o < 32; o <<= 1) {      // combine within the 32-lane subgroup
    unsigned long long vm = __shfl_xor(m, o, 64); m = vm > m ? vm : m;
    unsigned int vf = __shfl_xor(fcb, o, 64); if (vf > fcb) fcb = vf;
  }
  if (sub == 0) {
    float q = 0.f, u = 0.f;
    float a[8];
    #pragma unroll
    for (int j = 0; j < 8; ++j) a[j] = 0.f;
    if (m != 0ull) {
      q = __uint_as_float((unsigned)(m >> 32));
      unsigned idx = 0xFFFFFFFFu - (unsigned)(m & 0xFFFFFFFFull);
      if (idx < (unsigned)n) {
        const float* xp = x + (size_t)idx * 8;
        float s2 = 0.f;
        #pragma unroll
        for (int j = 0; j < 8; ++j) { float v = xp[j]; s2 = fmaf(v, v, s2); a[j] = 2.f * v; }
        u = 1.f - s2;
      }
    }
    PlainRec* pr = &ws->plain[k];
    #pragma unroll
    for (int j = 0; j < 8; ++j) pr->a[j] = a[j];
    pr->u = u; pr->q = q; pr->r0 = 0.f; pr->r1 = 0.f;
    float* rec = (float*)&ws->tab2[k & (KHALF - 1)];
    int h = k >> 8;
    #pragma unroll
    for (int j = 0; j < 8; ++j) rec[2 * j + h] = a[j];
    rec[16 + h] = u;
    rec[18 + h] = q;
    ws->fcenterf[k] = __uint_as_float(fcb);
  }
}

// ---------- dispatch 3: transposed main + atomics-fused final ----------
struct HR { float4 c0, c1, c2; };
__device__ __forceinline__ HR ldrec(const HitRec* __restrict__ p) {
  const float4* q4 = (const float4*)p;
  HR h; h.c0 = q4[0]; h.c1 = q4[1]; h.c2 = q4[2];
  return h;
}

#define STEP(H)                                                              \
  { v2f r_ = u2 + bc2((H).c2.x);                                             \
    r_ = __builtin_elementwise_fma(bc2((H).c0.x), a0, r_);                   \
    r_ = __builtin_elementwise_fma(bc2((H).c0.y), a1, r_);                   \
    r_ = __builtin_elementwise_fma(bc2((H).c0.z), a2, r_);                   \
    r_ = __builtin_elementwise_fma(bc2((H).c0.w), a3, r_);                   \
    r_ = __builtin_elementwise_fma(bc2((H).c1.x), a4, r_);                   \
    r_ = __builtin_elementwise_fma(bc2((H).c1.y), a5, r_);                   \
    r_ = __builtin_elementwise_fma(bc2((H).c1.z), a6, r_);                   \
    r_ = __builtin_elementwise_fma(bc2((H).c1.w), a7, r_);                   \
    v2f xv_ = __builtin_elementwise_min(__builtin_elementwise_max(r_, zero2), one2); \
    acc = __builtin_elementwise_fma(xv_, bc2((H).c2.y), acc); }

__global__ void __launch_bounds__(BLK) k_main(
    const HitRec* __restrict__ recs, const PairRec2* __restrict__ tab2,
    const PlainRec* __restrict__ plain, const int* __restrict__ kptr,
    int n, int hpb, Scratch* __restrict__ ws, float* __restrict__ out) {
  const float4* tp = (const float4*)&tab2[threadIdx.x];
  float4 t0 = tp[0], t1 = tp[1], t2 = tp[2], t3 = tp[3], t4 = tp[4];
  v2f a0 = {t0.x, t0.y}, a1 = {t0.z, t0.w}, a2 = {t1.x, t1.y}, a3 = {t1.z, t1.w};
  v2f a4 = {t2.x, t2.y}, a5 = {t2.z, t2.w}, a6 = {t3.x, t3.y}, a7 = {t3.z, t3.w};
  v2f u2 = {t4.x, t4.y}, q2 = {t4.z, t4.w};

  int i0 = blockIdx.x * hpb;
  int iend = i0 + hpb;                 // pads guarantee q_i = 0 past n

  // phase 1: member-term fixup (one term per hit in this slice)
  float fix = 0.f;
  for (int i = i0 + threadIdx.x; i < iend; i += BLK) {
    float4 c2 = recs[i].c2;
    int yi = __float_as_int(c2.z);
    if (yi >= 0 && yi < MAXK) {
      float4 h0 = recs[i].c0, h1 = recs[i].c1;
      const float4* pr4 = (const float4*)&plain[yi];
      float4 f0 = pr4[0], f1 = pr4[1], f2 = pr4[2];
      float r = f2.x + c2.x;
      r = fmaf(h0.x, f0.x, r); r = fmaf(h0.y, f0.y, r);
      r = fmaf(h0.z, f0.z, r); r = fmaf(h0.w, f0.w, r);
      r = fmaf(h1.x, f1.x, r); r = fmaf(h1.y, f1.y, r);
      r = fmaf(h1.z, f1.z, r); r = fmaf(h1.w, f1.w, r);
      float xinv = __builtin_amdgcn_fmed3f(r, 0.f, 1.f);
      float xd = fmaxf(1.f - r, 0.f);
      fix += (xd - xinv) * f2.y * c2.y;
    }
  }

  // phase 2: stream hits, 4-deep rotating prefetch, zero LDS, pure pk-f32
  v2f acc = {0.f, 0.f};
  v2f zero2 = {0.f, 0.f}, one2 = {1.f, 1.f};
  HR A = ldrec(recs + i0), B = ldrec(recs + i0 + 1),
     C = ldrec(recs + i0 + 2), D = ldrec(recs + i0 + 3);
  for (int i = i0; i < iend; i += 4) {
    STEP(A); A = ldrec(recs + i + 4);
    STEP(B); B = ldrec(recs + i + 5);
    STEP(C); C = ldrec(recs + i + 6);
    STEP(D); D = ldrec(recs + i + 7);
  }

  float lv = fmaf(acc[0], q2[0], fmaf(acc[1], q2[1], fix));
  for (int o = 32; o > 0; o >>= 1) lv += __shfl_down(lv, o, 64);
  __shared__ float rl[BLK / 64];
  int wid = threadIdx.x >> 6, lane = threadIdx.x & 63;
  if (lane == 0) rl[wid] = lv;
  __syncthreads();

  // fused final: relaxed agent-scope publish + acq_rel counter (no threadfence)
  __shared__ int amLast;
  if (threadIdx.x == 0) {
    float s = 0.f;
    #pragma unroll
    for (int w = 0; w < BLK / 64; ++w) s += rl[w];
    __hip_atomic_store(&ws->plv[blockIdx.x], s, __ATOMIC_RELAXED, __HIP_MEMORY_SCOPE_AGENT);
    unsigned old = __hip_atomic_fetch_add(&ws->ctr, 1u, __ATOMIC_ACQ_REL, __HIP_MEMORY_SCOPE_AGENT);
    amLast = (old == NBM - 1) ? 1 : 0;
  }
  __syncthreads();
  if (amLast) {
    int tid = threadIdx.x;
    float a = 0.f, b = 0.f, c = 0.f, d = 0.f;
    for (int t = tid; t < NBM; t += BLK)
      a += __hip_atomic_load(&ws->plv[t], __ATOMIC_RELAXED, __HIP_MEMORY_SCOPE_AGENT);
    for (int t = tid; t < GSC; t += BLK) { b += ws->partial_bkg[t]; c += ws->partial_cnt[t]; }
    for (int t = tid; t < MAXK; t += BLK) d += ws->fcenterf[t];   // 0 for t >= K
    __shared__ float sa[BLK], sb[BLK], sc[BLK], sd[BLK];
    sa[tid] = a; sb[tid] = b; sc[tid] = c; sd[tid] = d;
    __syncthreads();
    for (int o = BLK / 2; o > 0; o >>= 1) {
      if (tid < o) {
        sa[tid] += sa[tid + o]; sb[tid] += sb[tid + o];
        sc[tid] += sc[tid + o]; sd[tid] += sd[tid + o];
      }
      __syncthreads();
    }
    if (tid == 0) {
      int K = kptr[0]; if (K > MAXK) K = MAXK;
      float b1 = 1.f - sd[0] / (float)K;
      float b2 = sb[0] / sc[0];            // S_B = 1
      out[0] = (b1 + b2) + sa[0] / (float)n;
    }
  }
}

extern "C" void kernel_launch(void* const* d_in, const int* in_sizes, int n_in,
                              void* d_out, int out_size, void* d_ws, size_t ws_size,
                              hipStream_t stream) {
  const float* x = (const float*)d_in[0];
  const float* f = (const float*)d_in[1];
  const int*   y = (const int*)d_in[2];
  const int*  ei = (const int*)d_in[3];
  const int*  ej = (const int*)d_in[4];
  const int* kptr = (const int*)d_in[5];
  float* out = (float*)d_out;
  int n = in_sizes[1];
  int e = in_sizes[3];
  Scratch* ws = (Scratch*)d_ws;

  int hpb = ((n + NBM - 1) / NBM + 3) & ~3;   // hits per k_main block, multiple of 4
  int limpad = NBM * hpb;                      // 102400 for n=100k, < MAXN
  if (limpad > MAXN) limpad = MAXN;

  hipLaunchKernelGGL(k_scatprep, dim3(GSC),      dim3(BLK), 0, stream,
                     x, f, y, ei, ej, n, e, limpad, ws);
  hipLaunchKernelGGL(k_centers,  dim3(MAXK / 8), dim3(BLK), 0, stream, x, n, ws);
  hipLaunchKernelGGL(k_main,     dim3(NBM),      dim3(BLK), 0, stream,
                     ws->recs, ws->tab2, ws->plain, kptr, n, hpb, ws, out);
}